// Round 1
// baseline (105.272 us; speedup 1.0000x reference)
//
#include <hip/hip_runtime.h>
#include <hip/hip_bf16.h>

using short8  = __attribute__((ext_vector_type(8))) short;
using floatx4 = __attribute__((ext_vector_type(4))) float;

#define NROWS 8192
#define BHALF 4096
#define DDIM  128
// exp(sim - 10) = exp2((dot*10 - 10) * log2(e)) = exp2(dot*K1 - K1)
#define K1 14.426950408889634f

static __device__ __forceinline__ float fast_exp2(float x) {
#if __has_builtin(__builtin_amdgcn_exp2f)
    return __builtin_amdgcn_exp2f(x);
#else
    return exp2f(x);
#endif
}

static __device__ __forceinline__ unsigned short f2bf(float f) {
    unsigned int x = __builtin_bit_cast(unsigned int, f);
    x = (x + 0x7fffu + ((x >> 16) & 1u)) >> 16;   // RNE; inputs are finite
    return (unsigned short)x;
}

static __device__ __forceinline__ float bf2f(short s) {
    unsigned int x = ((unsigned int)(unsigned short)s) << 16;
    return __builtin_bit_cast(float, x);
}

// Kernel 1: L2-normalize each row of concat(emb0, emb1) -> bf16 zn.
// Also zeroes the per-row sum array and the scalar accumulator (ws is
// re-poisoned to 0xAA before every timed launch).
__global__ void k_norm(const float* __restrict__ e0, const float* __restrict__ e1,
                       unsigned short* __restrict__ zn,
                       float* __restrict__ Sarr, float* __restrict__ acc) {
    int tid  = threadIdx.x;            // 256
    int wid  = tid >> 6;
    int lane = tid & 63;
    int row  = blockIdx.x * 4 + wid;   // grid = 2048 -> rows 0..8191

    const float* src = (row < BHALF) ? (e0 + (size_t)row * DDIM)
                                     : (e1 + (size_t)(row - BHALF) * DDIM);
    float2 v = *(const float2*)(src + 2 * lane);
    float ss = v.x * v.x + v.y * v.y;
    #pragma unroll
    for (int m = 1; m < 64; m <<= 1) ss += __shfl_xor(ss, m);
    float rn = 1.0f / fmaxf(sqrtf(ss), 1e-8f);

    ushort2 uu;
    uu.x = f2bf(v.x * rn);
    uu.y = f2bf(v.y * rn);
    *(ushort2*)(zn + (size_t)row * DDIM + 2 * lane) = uu;

    if (blockIdx.x < 32) Sarr[blockIdx.x * 256 + tid] = 0.0f;
    if (blockIdx.x == 0 && tid == 0) acc[0] = 0.0f;
}

// Kernel 2: one wave per block. Wave owns 64 rows (4 MFMA row-tiles, A-frags
// in registers) and a 1024-column strip. For each 16-col tile: 4 mfma_16x16x32,
// exp2(fma), accumulate per-lane partial sums. Fixed max (=10) means partials
// just add -> atomicAdd per row at the end. Diagonal included (≈1), removed
// in k_final. Strip id in low 3 bits of blockIdx -> strip is XCD-L2-resident.
__global__ void __launch_bounds__(64) k_sim(const unsigned short* __restrict__ zn,
                                            float* __restrict__ Sarr) {
    int lane = threadIdx.x;
    int bid  = blockIdx.x;          // 1024 blocks
    int cs   = bid & 7;             // column strip 0..7 (== XCD under default round-robin)
    int rp   = bid >> 3;            // row panel 0..127
    int rb   = rp * 64;
    int g    = lane >> 4;           // k-group 0..3
    int c    = lane & 15;           // row/col within tile
    int ko   = g * 8;               // k offset of this lane's 8 contiguous elems

    // A fragments: 4 row-tiles x 4 k-slices, held in registers (64 VGPRs)
    short8 a[4][4];
    #pragma unroll
    for (int rt = 0; rt < 4; ++rt)
        #pragma unroll
        for (int kk = 0; kk < 4; ++kk)
            a[rt][kk] = *(const short8*)(zn + (size_t)(rb + rt * 16 + c) * DDIM + kk * 32 + ko);

    floatx4 s[4];
    #pragma unroll
    for (int rt = 0; rt < 4; ++rt) s[rt] = (floatx4){0.f, 0.f, 0.f, 0.f};

    const unsigned short* pB = zn + (size_t)(cs * 1024 + c) * DDIM + ko;

    #pragma unroll 2
    for (int ct = 0; ct < 64; ++ct) {
        short8 b0 = *(const short8*)(pB);
        short8 b1 = *(const short8*)(pB + 32);
        short8 b2 = *(const short8*)(pB + 64);
        short8 b3 = *(const short8*)(pB + 96);
        pB += 16 * DDIM;
        #pragma unroll
        for (int rt = 0; rt < 4; ++rt) {
            floatx4 accv = (floatx4){0.f, 0.f, 0.f, 0.f};
            accv = __builtin_amdgcn_mfma_f32_16x16x32_bf16(a[rt][0], b0, accv, 0, 0, 0);
            accv = __builtin_amdgcn_mfma_f32_16x16x32_bf16(a[rt][1], b1, accv, 0, 0, 0);
            accv = __builtin_amdgcn_mfma_f32_16x16x32_bf16(a[rt][2], b2, accv, 0, 0, 0);
            accv = __builtin_amdgcn_mfma_f32_16x16x32_bf16(a[rt][3], b3, accv, 0, 0, 0);
            #pragma unroll
            for (int r = 0; r < 4; ++r)
                s[rt][r] += fast_exp2(fmaf(accv[r], K1, -K1));
        }
    }

    // Reduce each row's 16 column-slots (lanes with same g) -> full partial sum
    #pragma unroll
    for (int rt = 0; rt < 4; ++rt)
        #pragma unroll
        for (int r = 0; r < 4; ++r) {
            float v = s[rt][r];
            v += __shfl_xor(v, 1);
            v += __shfl_xor(v, 2);
            v += __shfl_xor(v, 4);
            v += __shfl_xor(v, 8);
            s[rt][r] = v;
        }

    if (c == 0) {
        #pragma unroll
        for (int rt = 0; rt < 4; ++rt)
            #pragma unroll
            for (int r = 0; r < 4; ++r)
                atomicAdd(&Sarr[rb + rt * 16 + 4 * g + r], s[rt][r]);
    }
}

// Kernel 3: per row i: term = log(S_i - 1) + 10 - 10*dot(zn_i, zn_{i^4096});
// wave handles 16 rows (4 lanes per row), block-free shuffle reduce, one
// atomicAdd per wave.
__global__ void k_final(const unsigned short* __restrict__ zn,
                        const float* __restrict__ Sarr, float* __restrict__ acc) {
    int tid  = threadIdx.x;           // 256
    int lane = tid & 63;
    int wid  = tid >> 6;
    int w    = blockIdx.x * 4 + wid;  // 0..511 (grid = 128)
    int row  = w * 16 + (lane >> 2);
    int q    = lane & 3;
    int prow = row ^ BHALF;

    const unsigned short* pa = zn + (size_t)row  * DDIM + q * 32;
    const unsigned short* pb = zn + (size_t)prow * DDIM + q * 32;
    float dot = 0.f;
    #pragma unroll
    for (int kk = 0; kk < 4; ++kk) {
        short8 va = *(const short8*)(pa + kk * 8);
        short8 vb = *(const short8*)(pb + kk * 8);
        #pragma unroll
        for (int j = 0; j < 8; ++j)
            dot = fmaf(bf2f(va[j]), bf2f(vb[j]), dot);
    }
    dot += __shfl_xor(dot, 1);
    dot += __shfl_xor(dot, 2);

    float term = 0.f;
    if (q == 0) {
        float S = Sarr[row] - 1.0f;   // remove diagonal's exp(0)=1
        term = logf(S) + 10.0f - dot * 10.0f;
    }
    term += __shfl_xor(term, 4);
    term += __shfl_xor(term, 8);
    term += __shfl_xor(term, 16);
    term += __shfl_xor(term, 32);
    if (lane == 0) atomicAdd(acc, term);
}

__global__ void k_out(const float* __restrict__ acc, float* __restrict__ out) {
    out[0] = acc[0] * (1.0f / 8192.0f);
}

extern "C" void kernel_launch(void* const* d_in, const int* in_sizes, int n_in,
                              void* d_out, int out_size, void* d_ws, size_t ws_size,
                              hipStream_t stream) {
    const float* e0 = (const float*)d_in[0];
    const float* e1 = (const float*)d_in[1];
    float* out = (float*)d_out;

    unsigned short* zn  = (unsigned short*)d_ws;                       // 8192*128*2 = 2 MiB
    float* Sarr = (float*)((char*)d_ws + (size_t)NROWS * DDIM * 2);    // 32 KiB
    float* acc  = Sarr + NROWS;                                        // 4 B

    k_norm<<<2048, 256, 0, stream>>>(e0, e1, zn, Sarr, acc);
    k_sim<<<1024, 64, 0, stream>>>(zn, Sarr);
    k_final<<<128, 256, 0, stream>>>(zn, Sarr, acc);
    k_out<<<1, 1, 0, stream>>>(acc, out);
}